// Round 8
// baseline (186.249 us; speedup 1.0000x reference)
//
#include <hip/hip_runtime.h>
#include <stdint.h>

#define IN_F  4096
#define OUT_F 4096
#define BW    512
#define WB2   1280   // padded k-window per 256-col tile: [bcol-512, bcol+768)
#define BM    256
#define BN    256

typedef __bf16 bf16x8 __attribute__((ext_vector_type(8)));
typedef float  f32x4  __attribute__((ext_vector_type(4)));

__device__ __forceinline__ int band_start(int o) {
    if (o <= 512)  return o * 513 + ((o * (o - 1)) >> 1);
    if (o <= 3584) return 393472 + (o - 512) * 1025;
    const int d = o - 3584;
    return 3542272 + (((1024 + 4609 - o) * d) >> 1);
}

__device__ __forceinline__ uint16_t f32_to_bf16(float f) {
    uint32_t u = __builtin_bit_cast(uint32_t, f);
    u += 0x7FFFu + ((u >> 16) & 1u);   // RNE
    return (uint16_t)(u >> 16);
}

// ---- pass 1: x fp32 -> bf16 dense [M][4096]
__global__ __launch_bounds__(256) void cvt_x(const float* __restrict__ x,
                                             uint16_t* __restrict__ xb, int n4) {
    const int stride = gridDim.x * 256;
    for (int i = blockIdx.x * 256 + threadIdx.x; i < n4; i += stride) {
        const float4 v = reinterpret_cast<const float4*>(x)[i];
        const uint32_t lo = (uint32_t)f32_to_bf16(v.x) | ((uint32_t)f32_to_bf16(v.y) << 16);
        const uint32_t hi = (uint32_t)f32_to_bf16(v.z) | ((uint32_t)f32_to_bf16(v.w) << 16);
        reinterpret_cast<uint2*>(xb)[i] = make_uint2(lo, hi);
    }
}

// ---- pass 2: densify band -> wd[o][j], j indexes k = (o&~255)-512+j, zero outside band
__global__ __launch_bounds__(256) void cvt_w(const float* __restrict__ wv,
                                             uint16_t* __restrict__ wd) {
    const int o = blockIdx.y;
    const int j = blockIdx.x * 256 + threadIdx.x;     // 0..1279
    const int i = (o & ~(BM - 1)) - BW + j;
    uint16_t v = 0;
    if (i >= o - BW && i <= o + BW && i >= 0 && i < IN_F) {
        const int lo = (o > BW) ? (o - BW) : 0;
        v = f32_to_bf16(wv[band_start(o) + (i - lo)]);
    }
    wd[o * WB2 + j] = v;
}

// ---- pass 3: 256x256, BK=64. A: LDS ring-4 (128 KB). B: direct L2->reg,
// double-buffered (no barriers). 1 barrier + 1 counted vmcnt per K64 tile.
__global__ __launch_bounds__(512, 1) void band_gemm_v8(
    const uint16_t* __restrict__ xb,
    const uint16_t* __restrict__ wd,
    const float* __restrict__ bias,
    float* __restrict__ out)
{
    __shared__ __align__(128) uint8_t lds[131072];   // 4 A-slots x 32 KB

    // bx-grouped XCD mapping: XCD x owns column panels {2x, 2x+1}; B L2-hot
    const int id  = blockIdx.x;
    const int xcd = id & 7;
    const int r   = id >> 3;
    const int bx  = 2 * xcd + (r & 1);
    const int by  = r >> 1;
    const int brow = by * BM;
    const int bcol = bx * BN;

    const int wlo    = bcol - BW;
    const int kstart = wlo > 0 ? wlo : 0;
    const int kend   = (bcol + BN + BW) < IN_F ? (bcol + BN + BW) : IN_F;
    const int nt     = (kend - kstart) >> 6;      // 12/16/20 (always even)
    const int j0     = kstart - wlo;

    const int tid  = threadIdx.x;
    const int w    = tid >> 6;
    const int lane = tid & 63;
    const int ln   = lane & 15;
    const int kc   = lane >> 4;
    const int wm   = w >> 2;            // 0..1  (M half, 128 rows)
    const int wn   = w & 3;             // 0..3  (N quarter, 64 cols)

    // A staging: unit = 64 rows x 128 B; LDS(row,c) holds global chunk c ^ (row&7)
    const int srow = tid >> 3;
    const int csrc = (tid & 7) ^ (srow & 7);
    const uint16_t* aSrc = xb + (size_t)(brow + srow) * IN_F + kstart + csrc * 8;

#define GLOAD(srcp, dst_off)                                                             \
    __builtin_amdgcn_global_load_lds(                                                    \
        (const __attribute__((address_space(1))) uint32_t*)(srcp),                       \
        (__attribute__((address_space(3))) uint32_t*)(lds + (dst_off) + (w << 10)),      \
        16, 0, 0)

#define STAGE_A(v_, slot_) { const uint16_t* as_ = aSrc + (v_) * 64;                     \
        GLOAD(as_,                        (slot_) * 32768 + 0);                          \
        GLOAD(as_ + (size_t)64  * IN_F,   (slot_) * 32768 + 8192);                       \
        GLOAD(as_ + (size_t)128 * IN_F,   (slot_) * 32768 + 16384);                      \
        GLOAD(as_ + (size_t)192 * IN_F,   (slot_) * 32768 + 24576); }

    // B direct-to-reg: lane(ln,kc) loads wd[bcol+wn*64+n*16+ln][j0+v*64+ks*32+kc*8 ..+8]
    // == exactly the bytes the proven LDS path delivered to this lane.
    const uint16_t* bPtr = wd + (size_t)(bcol + wn * 64 + ln) * WB2 + j0 + kc * 8;

#define LOADB(DST, v_) {                                                                 \
    _Pragma("unroll")                                                                    \
    for (int n_ = 0; n_ < 4; ++n_) {                                                     \
        _Pragma("unroll")                                                                \
        for (int ks_ = 0; ks_ < 2; ++ks_)                                                \
            DST[n_][ks_] = *(const bf16x8*)(bPtr + (size_t)n_ * 16 * WB2 + (v_) * 64 + ks_ * 32); \
    } }

    // A fragment offsets within a 32 KB slot (proven zero-conflict swizzle); k1 = ^64
    const int cswz = (kc ^ (ln & 7)) << 4;
    int aOff[8];
    #pragma unroll
    for (int a = 0; a < 8; ++a) aOff[a] = ((wm * 128 + a * 16 + ln) << 7) + cswz;

#define COMPUTE(BB, SB) {                                                                \
    _Pragma("unroll")                                                                    \
    for (int mq = 0; mq < 2; ++mq) {                                                     \
        bf16x8 af[4][2];                                                                 \
        _Pragma("unroll")                                                                \
        for (int a_ = 0; a_ < 4; ++a_) {                                                 \
            af[a_][0] = *(const bf16x8*)(lds + (SB) + aOff[mq * 4 + a_]);                \
            af[a_][1] = *(const bf16x8*)(lds + (SB) + (aOff[mq * 4 + a_] ^ 64));         \
        }                                                                                \
        __builtin_amdgcn_s_setprio(1);                                                   \
        _Pragma("unroll")                                                                \
        for (int a_ = 0; a_ < 4; ++a_) {                                                 \
            _Pragma("unroll")                                                            \
            for (int n_ = 0; n_ < 4; ++n_) {                                             \
                acc[mq * 4 + a_][n_] = __builtin_amdgcn_mfma_f32_16x16x32_bf16(          \
                    af[a_][0], BB[n_][0], acc[mq * 4 + a_][n_], 0, 0, 0);                \
                acc[mq * 4 + a_][n_] = __builtin_amdgcn_mfma_f32_16x16x32_bf16(          \
                    af[a_][1], BB[n_][1], acc[mq * 4 + a_][n_], 0, 0, 0);                \
            } }                                                                          \
        __builtin_amdgcn_s_setprio(0);                                                   \
    } }

    // per-tile end sync: retire {A4(v+1), B8(v+1)}, keep A4(v+2) in flight
#define TILE_END(cond_)                                                                  \
    if (cond_) { asm volatile("s_waitcnt vmcnt(4)" ::: "memory"); }                      \
    else       { asm volatile("s_waitcnt vmcnt(0)" ::: "memory"); }                      \
    __builtin_amdgcn_s_barrier();                                                        \
    asm volatile("" ::: "memory");

    f32x4 acc[8][4] = {};
    bf16x8 bEv[4][2], bOd[4][2];

    // prologue — mirrors steady-state ledger: [B8(0), A4(0), A4(1)] -> vmcnt(4)
    LOADB(bEv, 0);
    STAGE_A(0, 0);
    STAGE_A(1, 1);
    asm volatile("s_waitcnt vmcnt(4)" ::: "memory");
    __builtin_amdgcn_s_barrier();
    asm volatile("" ::: "memory");

    const int nt2 = nt >> 1;
    for (int t = 0; t < nt2; ++t) {
        const int v0 = 2 * t;
        const int s0 = (t & 1) << 1;        // v0 -> slot s0, v1 -> s0+1
        // ---- tile v0 (B = bEv)
        LOADB(bOd, v0 + 1);                 // v0+1 <= nt-1 always
        if (v0 + 2 < nt) STAGE_A(v0 + 2, s0 ^ 2);
        __builtin_amdgcn_sched_barrier(0);  // pin issue above compute
        COMPUTE(bEv, s0 * 32768);
        TILE_END(v0 + 2 < nt);
        // ---- tile v1 (B = bOd)
        if (v0 + 2 < nt) LOADB(bEv, v0 + 2);
        if (v0 + 3 < nt) STAGE_A(v0 + 3, (s0 ^ 2) + 1);
        __builtin_amdgcn_sched_barrier(0);
        COMPUTE(bOd, (s0 + 1) * 32768);
        TILE_END(v0 + 3 < nt);
    }
#undef STAGE_A
#undef GLOAD

    // epilogue: C/D map col = lane&15, row = (lane>>4)*4 + q  (verified R2-R7)
    const int ocol = bcol + wn * 64 + ln;
    float bsv[4];
    #pragma unroll
    for (int n = 0; n < 4; ++n) bsv[n] = bias[ocol + n * 16];

    #pragma unroll
    for (int a = 0; a < 8; ++a) {
        #pragma unroll
        for (int q = 0; q < 4; ++q) {
            const int row = brow + wm * 128 + a * 16 + (kc << 2) + q;
            float* po = out + (size_t)row * OUT_F + ocol;
            #pragma unroll
            for (int n = 0; n < 4; ++n)
                po[n * 16] = acc[a][n][q] + bsv[n];
        }
    }
}

// ---- fallback (ws too small / odd M): fp32 tiled kernel, known correct
__global__ __launch_bounds__(256) void band_gemm_f32(
    const float* __restrict__ x, const float* __restrict__ wv,
    const float* __restrict__ bias, float* __restrict__ out, int M)
{
    __shared__ float Xs[128][33];
    __shared__ float Ws[32][130];
    const int tid = threadIdx.x;
    const int tx = tid & 15, ty = tid >> 4;
    const int bcol = blockIdx.x * 128, brow = blockIdx.y * 128;
    const int klo = (bcol >= BW) ? (bcol - BW) : 0;
    const int khi = min(IN_F, bcol + 128 + BW);
    float acc[8][8];
    #pragma unroll
    for (int a = 0; a < 8; ++a)
        #pragma unroll
        for (int b = 0; b < 8; ++b) acc[a][b] = 0.f;
    const int xc4 = (tid & 7) * 4, xr0 = tid >> 3;
    const int wc = tid & 31, wr0 = tid >> 5;
    for (int k0 = klo; k0 < khi; k0 += 32) {
        #pragma unroll
        for (int p = 0; p < 4; ++p) {
            const int rr = xr0 + 32 * p;
            const float4 v = *reinterpret_cast<const float4*>(&x[(size_t)(brow + rr) * IN_F + (k0 + xc4)]);
            Xs[rr][xc4 + 0] = v.x; Xs[rr][xc4 + 1] = v.y; Xs[rr][xc4 + 2] = v.z; Xs[rr][xc4 + 3] = v.w;
        }
        const int i = k0 + wc;
        #pragma unroll
        for (int p = 0; p < 16; ++p) {
            const int rr = wr0 + 8 * p;
            const int o = bcol + rr;
            const int lo = (o >= BW) ? (o - BW) : 0;
            float v = 0.f;
            if (i >= o - BW && i <= o + BW) v = wv[band_start(o) + (i - lo)];
            Ws[wc][rr] = v;
        }
        __syncthreads();
        #pragma unroll
        for (int k = 0; k < 32; ++k) {
            float am[8];
            #pragma unroll
            for (int a = 0; a < 8; ++a) am[a] = Xs[ty * 8 + a][k];
            float bo[8];
            #pragma unroll
            for (int b = 0; b < 4; ++b) { bo[b] = Ws[k][tx * 4 + b]; bo[4 + b] = Ws[k][tx * 4 + 64 + b]; }
            #pragma unroll
            for (int a = 0; a < 8; ++a)
                #pragma unroll
                for (int b = 0; b < 8; ++b) acc[a][b] = fmaf(am[a], bo[b], acc[a][b]);
        }
        __syncthreads();
    }
    #pragma unroll
    for (int a = 0; a < 8; ++a) {
        const size_t row = (size_t)(brow + ty * 8 + a);
        #pragma unroll
        for (int b = 0; b < 4; ++b) {
            out[row * OUT_F + bcol + tx * 4 + b]      = acc[a][b]     + bias[bcol + tx * 4 + b];
            out[row * OUT_F + bcol + tx * 4 + 64 + b] = acc[a][4 + b] + bias[bcol + tx * 4 + 64 + b];
        }
    }
}

extern "C" void kernel_launch(void* const* d_in, const int* in_sizes, int n_in,
                              void* d_out, int out_size, void* d_ws, size_t ws_size,
                              hipStream_t stream) {
    const float* x    = (const float*)d_in[0];
    const float* wv   = (const float*)d_in[1];
    const float* bias = (const float*)d_in[2];
    float* out        = (float*)d_out;

    const int M = in_sizes[0] / IN_F;                         // 8192
    const size_t xb_bytes = (size_t)M * IN_F * 2;             // 64 MB
    const size_t wd_bytes = (size_t)OUT_F * WB2 * 2;          // 10.5 MB

    if (ws_size >= xb_bytes + wd_bytes && (M % BM) == 0) {
        uint16_t* xb  = (uint16_t*)d_ws;
        uint16_t* wdp = (uint16_t*)((uint8_t*)d_ws + xb_bytes);
        cvt_x<<<2048, 256, 0, stream>>>(x, xb, M * IN_F / 4);
        cvt_w<<<dim3(WB2 / 256, OUT_F), 256, 0, stream>>>(wv, wdp);
        band_gemm_v8<<<(M / BM) * (OUT_F / BN), 512, 0, stream>>>(xb, wdp, bias, out);
    } else {
        dim3 grid(OUT_F / 128, M / 128);
        band_gemm_f32<<<grid, 256, 0, stream>>>(x, wv, bias, out, M);
    }
}

// Round 9
// 140.443 us; speedup vs baseline: 1.3262x; 1.3262x over previous
//
#include <hip/hip_runtime.h>
#include <stdint.h>

#define IN_F  4096
#define OUT_F 4096
#define BW    512
#define WB2   1280   // padded k-window per 256-col tile: [bcol-512, bcol+768)
#define BM    256
#define BN    256

typedef __bf16 bf16x8 __attribute__((ext_vector_type(8)));
typedef float  f32x4  __attribute__((ext_vector_type(4)));

__device__ __forceinline__ int band_start(int o) {
    if (o <= 512)  return o * 513 + ((o * (o - 1)) >> 1);
    if (o <= 3584) return 393472 + (o - 512) * 1025;
    const int d = o - 3584;
    return 3542272 + (((1024 + 4609 - o) * d) >> 1);
}

__device__ __forceinline__ uint16_t f32_to_bf16(float f) {
    uint32_t u = __builtin_bit_cast(uint32_t, f);
    u += 0x7FFFu + ((u >> 16) & 1u);   // RNE
    return (uint16_t)(u >> 16);
}

// ---- pass 1: x fp32 -> bf16 dense [M][4096]
__global__ __launch_bounds__(256) void cvt_x(const float* __restrict__ x,
                                             uint16_t* __restrict__ xb, int n4) {
    const int stride = gridDim.x * 256;
    for (int i = blockIdx.x * 256 + threadIdx.x; i < n4; i += stride) {
        const float4 v = reinterpret_cast<const float4*>(x)[i];
        const uint32_t lo = (uint32_t)f32_to_bf16(v.x) | ((uint32_t)f32_to_bf16(v.y) << 16);
        const uint32_t hi = (uint32_t)f32_to_bf16(v.z) | ((uint32_t)f32_to_bf16(v.w) << 16);
        reinterpret_cast<uint2*>(xb)[i] = make_uint2(lo, hi);
    }
}

// ---- pass 2: densify band -> wd[o][j], j indexes k = (o&~255)-512+j, zero outside band
__global__ __launch_bounds__(256) void cvt_w(const float* __restrict__ wv,
                                             uint16_t* __restrict__ wd) {
    const int o = blockIdx.y;
    const int j = blockIdx.x * 256 + threadIdx.x;     // 0..1279
    const int i = (o & ~(BM - 1)) - BW + j;
    uint16_t v = 0;
    if (i >= o - BW && i <= o + BW && i >= 0 && i < IN_F) {
        const int lo = (o > BW) ? (o - BW) : 0;
        v = f32_to_bf16(wv[band_start(o) + (i - lo)]);
    }
    wd[o * WB2 + j] = v;
}

// ---- pass 3: 256x256, BK=64, ring-9 half-tile units (144 KB), counted vmcnt(2),
// ONE barrier per K64 tile, quadrant-rotation fragment reuse.
__global__ __launch_bounds__(512, 1) void band_gemm_v9(
    const uint16_t* __restrict__ xb,
    const uint16_t* __restrict__ wd,
    const float* __restrict__ bias,
    float* __restrict__ out)
{
    __shared__ __align__(128) uint8_t lds[9 * 16384];   // 144 KB, 9 unit slots

    // bx-grouped XCD mapping: XCD x owns column panels {2x, 2x+1}; B stays L2-hot
    const int id  = blockIdx.x;
    const int xcd = id & 7;
    const int r   = id >> 3;
    const int bx  = 2 * xcd + (r & 1);
    const int by  = r >> 1;
    const int brow = by * BM;
    const int bcol = bx * BN;

    const int wlo    = bcol - BW;
    const int kstart = wlo > 0 ? wlo : 0;
    const int kend   = (bcol + BN + BW) < IN_F ? (bcol + BN + BW) : IN_F;
    const int nt     = (kend - kstart) >> 6;      // 12/16/20 K64 tiles
    const int j0     = kstart - wlo;

    const int tid  = threadIdx.x;
    const int w    = tid >> 6;
    const int lane = tid & 63;
    const int ln   = lane & 15;
    const int kc   = lane >> 4;
    const int wm   = w >> 2;            // 0..1  (M half, 128 rows)
    const int wn   = w & 3;             // 0..3  (N quarter, 64 cols)

    // staging: unit = 128 rows x 128 B (16 KB = 2 gloads of 64 rows each)
    // LDS(row,c) holds global chunk c ^ (row&7)  [chunk = 16 B] -> pre-swizzled src
    const int srow = tid >> 3;          // 0..63
    const int csrc = (tid & 7) ^ (srow & 7);
    const uint16_t* aSrc = xb + (size_t)(brow + srow) * IN_F + kstart + csrc * 8;
    const uint16_t* bSrc = wd + (size_t)(bcol + srow) * WB2 + j0 + csrc * 8;

#define GLOAD(srcp, dst_off)                                                             \
    __builtin_amdgcn_global_load_lds(                                                    \
        (const __attribute__((address_space(1))) uint32_t*)(srcp),                       \
        (__attribute__((address_space(3))) uint32_t*)(lds + (dst_off) + (w << 10)),      \
        16, 0, 0)

    // unit j of tile w_: j=0 A rows 0-127, j=1 B rows 0-127, j=2 A rows 128-255, j=3 B rows 128-255
#define STG_UNIT(w_, j_, slot_) {                                                        \
        if (((j_) & 1) == 0) {                                                           \
            const uint16_t* p_ = aSrc + (size_t)(((j_) >> 1) * 128) * IN_F + (w_) * 64;  \
            GLOAD(p_, (slot_) << 14);                                                    \
            GLOAD(p_ + (size_t)64 * IN_F, ((slot_) << 14) + 8192);                       \
        } else {                                                                         \
            const uint16_t* p_ = bSrc + (size_t)(((j_) >> 1) * 128) * WB2 + (w_) * 64;   \
            GLOAD(p_, (slot_) << 14);                                                    \
            GLOAD(p_ + (size_t)64 * WB2, ((slot_) << 14) + 8192);                        \
        } }

    // fragment addressing within a 16 KB unit (proven zero-conflict); k-step1 = ^64
    const int cswz = (kc ^ (ln & 7)) << 4;

#define LD_A(BASE, MQ) {                                                                 \
    _Pragma("unroll")                                                                    \
    for (int s_ = 0; s_ < 4; ++s_) {                                                     \
        const int off_ = (BASE) + (((MQ) * 64 + s_ * 16 + ln) << 7) + cswz;              \
        am[s_][0] = *(const bf16x8*)(lds + off_);                                        \
        am[s_][1] = *(const bf16x8*)(lds + (off_ ^ 64));                                 \
    } }
#define LD_B(DST, BASE, NQ) {                                                            \
    _Pragma("unroll")                                                                    \
    for (int s_ = 0; s_ < 2; ++s_) {                                                     \
        const int off_ = (BASE) + (((wn & 1) * 64 + (NQ) * 32 + s_ * 16 + ln) << 7) + cswz; \
        DST[s_][0] = *(const bf16x8*)(lds + off_);                                       \
        DST[s_][1] = *(const bf16x8*)(lds + (off_ ^ 64));                                \
    } }
#define MFMAPH(MROW, NCOL, BB) {                                                         \
    __builtin_amdgcn_s_setprio(1);                                                       \
    _Pragma("unroll")                                                                    \
    for (int a_ = 0; a_ < 4; ++a_) {                                                     \
        _Pragma("unroll")                                                                \
        for (int n_ = 0; n_ < 2; ++n_) {                                                 \
            acc[(MROW) + a_][(NCOL) + n_] = __builtin_amdgcn_mfma_f32_16x16x32_bf16(     \
                am[a_][0], BB[n_][0], acc[(MROW) + a_][(NCOL) + n_], 0, 0, 0);           \
            acc[(MROW) + a_][(NCOL) + n_] = __builtin_amdgcn_mfma_f32_16x16x32_bf16(     \
                am[a_][1], BB[n_][1], acc[(MROW) + a_][(NCOL) + n_], 0, 0, 0);           \
        } }                                                                              \
    __builtin_amdgcn_s_setprio(0); }

    f32x4 acc[8][4] = {};
    bf16x8 am[4][2], bn0[2][2], bn1[2][2];

    // prologue: stage units idx 0..4 = {A0,B0,A1,B1}(0), A0(1); retire tile 0, keep A0(1)
    STG_UNIT(0, 0, 0); STG_UNIT(0, 1, 1); STG_UNIT(0, 2, 2); STG_UNIT(0, 3, 3);
    STG_UNIT(1, 0, 4);
    asm volatile("s_waitcnt vmcnt(2)" ::: "memory");
    __builtin_amdgcn_s_barrier();

    int s4v = 0;                       // (4v) % 9
    for (int v = 0; v < nt; ++v) {
        // unit slot bases for this tile
        int sA = s4v + (wm << 1);           if (sA >= 9) sA -= 9;
        int sB = s4v + 1 + ((wn >> 1) << 1); if (sB >= 9) sB -= 9;
        const int aBase = sA << 14, bBase = sB << 14;
        // stage slots for idx 4v+5 .. 4v+8
        int st0 = s4v + 5; if (st0 >= 9) st0 -= 9;
        int st1 = st0 + 1; if (st1 >= 9) st1 -= 9;
        int st2 = st1 + 1; if (st2 >= 9) st2 -= 9;
        int st3 = st2 + 1; if (st3 >= 9) st3 -= 9;
        const bool stg_q012 = (v + 1 < nt);
        const bool stg_q3   = (v + 2 < nt);

        // q0: quadrant (m0,n0); stage B0(v+1)
        LD_A(aBase, 0);
        LD_B(bn0, bBase, 0);
        if (stg_q012) STG_UNIT(v + 1, 1, st0);
        MFMAPH(0, 0, bn0);
        // q1: (m0,n1); stage A1(v+1)
        LD_B(bn1, bBase, 1);
        if (stg_q012) STG_UNIT(v + 1, 2, st1);
        MFMAPH(0, 2, bn1);
        // q2: (m1,n1); stage B1(v+1)
        LD_A(aBase, 1);
        if (stg_q012) STG_UNIT(v + 1, 3, st2);
        MFMAPH(4, 2, bn1);
        // q3: (m1,n0); stage A0(v+2)
        if (stg_q3) STG_UNIT(v + 2, 0, st3);
        MFMAPH(4, 0, bn0);

        // boundary: retire tile v+1's 4 units, keep A0(v+2) (2 loads) in flight
        if (v + 1 < nt) {
            if (v + 2 < nt) { asm volatile("s_waitcnt vmcnt(2)" ::: "memory"); }
            else            { asm volatile("s_waitcnt vmcnt(0)" ::: "memory"); }
            __builtin_amdgcn_s_barrier();
        }
        s4v += 4; if (s4v >= 9) s4v -= 9;
    }
#undef STG_UNIT
#undef GLOAD

    // epilogue: C/D map col = lane&15, row = (lane>>4)*4 + q  (verified R2-R8)
    const int ocol = bcol + wn * 64 + ln;
    float bsv[4];
    #pragma unroll
    for (int n = 0; n < 4; ++n) bsv[n] = bias[ocol + n * 16];

    #pragma unroll
    for (int a = 0; a < 8; ++a) {
        #pragma unroll
        for (int q = 0; q < 4; ++q) {
            const int row = brow + wm * 128 + a * 16 + (kc << 2) + q;
            float* po = out + (size_t)row * OUT_F + ocol;
            #pragma unroll
            for (int n = 0; n < 4; ++n)
                po[n * 16] = acc[a][n][q] + bsv[n];
        }
    }
}

// ---- fallback (ws too small / odd M): fp32 tiled kernel, known correct
__global__ __launch_bounds__(256) void band_gemm_f32(
    const float* __restrict__ x, const float* __restrict__ wv,
    const float* __restrict__ bias, float* __restrict__ out, int M)
{
    __shared__ float Xs[128][33];
    __shared__ float Ws[32][130];
    const int tid = threadIdx.x;
    const int tx = tid & 15, ty = tid >> 4;
    const int bcol = blockIdx.x * 128, brow = blockIdx.y * 128;
    const int klo = (bcol >= BW) ? (bcol - BW) : 0;
    const int khi = min(IN_F, bcol + 128 + BW);
    float acc[8][8];
    #pragma unroll
    for (int a = 0; a < 8; ++a)
        #pragma unroll
        for (int b = 0; b < 8; ++b) acc[a][b] = 0.f;
    const int xc4 = (tid & 7) * 4, xr0 = tid >> 3;
    const int wc = tid & 31, wr0 = tid >> 5;
    for (int k0 = klo; k0 < khi; k0 += 32) {
        #pragma unroll
        for (int p = 0; p < 4; ++p) {
            const int rr = xr0 + 32 * p;
            const float4 v = *reinterpret_cast<const float4*>(&x[(size_t)(brow + rr) * IN_F + (k0 + xc4)]);
            Xs[rr][xc4 + 0] = v.x; Xs[rr][xc4 + 1] = v.y; Xs[rr][xc4 + 2] = v.z; Xs[rr][xc4 + 3] = v.w;
        }
        const int i = k0 + wc;
        #pragma unroll
        for (int p = 0; p < 16; ++p) {
            const int rr = wr0 + 8 * p;
            const int o = bcol + rr;
            const int lo = (o >= BW) ? (o - BW) : 0;
            float v = 0.f;
            if (i >= o - BW && i <= o + BW) v = wv[band_start(o) + (i - lo)];
            Ws[wc][rr] = v;
        }
        __syncthreads();
        #pragma unroll
        for (int k = 0; k < 32; ++k) {
            float amv[8];
            #pragma unroll
            for (int a = 0; a < 8; ++a) amv[a] = Xs[ty * 8 + a][k];
            float bo[8];
            #pragma unroll
            for (int b = 0; b < 4; ++b) { bo[b] = Ws[k][tx * 4 + b]; bo[4 + b] = Ws[k][tx * 4 + 64 + b]; }
            #pragma unroll
            for (int a = 0; a < 8; ++a)
                #pragma unroll
                for (int b = 0; b < 8; ++b) acc[a][b] = fmaf(amv[a], bo[b], acc[a][b]);
        }
        __syncthreads();
    }
    #pragma unroll
    for (int a = 0; a < 8; ++a) {
        const size_t row = (size_t)(brow + ty * 8 + a);
        #pragma unroll
        for (int b = 0; b < 4; ++b) {
            out[row * OUT_F + bcol + tx * 4 + b]      = acc[a][b]     + bias[bcol + tx * 4 + b];
            out[row * OUT_F + bcol + tx * 4 + 64 + b] = acc[a][4 + b] + bias[bcol + tx * 4 + 64 + b];
        }
    }
}

extern "C" void kernel_launch(void* const* d_in, const int* in_sizes, int n_in,
                              void* d_out, int out_size, void* d_ws, size_t ws_size,
                              hipStream_t stream) {
    const float* x    = (const float*)d_in[0];
    const float* wv   = (const float*)d_in[1];
    const float* bias = (const float*)d_in[2];
    float* out        = (float*)d_out;

    const int M = in_sizes[0] / IN_F;                         // 8192
    const size_t xb_bytes = (size_t)M * IN_F * 2;             // 64 MB
    const size_t wd_bytes = (size_t)OUT_F * WB2 * 2;          // 10.5 MB

    if (ws_size >= xb_bytes + wd_bytes && (M % BM) == 0) {
        uint16_t* xb  = (uint16_t*)d_ws;
        uint16_t* wdp = (uint16_t*)((uint8_t*)d_ws + xb_bytes);
        cvt_x<<<2048, 256, 0, stream>>>(x, xb, M * IN_F / 4);
        cvt_w<<<dim3(WB2 / 256, OUT_F), 256, 0, stream>>>(wv, wdp);
        band_gemm_v9<<<(M / BM) * (OUT_F / BN), 512, 0, stream>>>(xb, wdp, bias, out);
    } else {
        dim3 grid(OUT_F / 128, M / 128);
        band_gemm_f32<<<grid, 256, 0, stream>>>(x, wv, bias, out, M);
    }
}

// Round 10
// 139.308 us; speedup vs baseline: 1.3370x; 1.0081x over previous
//
#include <hip/hip_runtime.h>
#include <stdint.h>

#define IN_F  4096
#define OUT_F 4096
#define BW    512
#define WB2   1280   // padded k-window per 256-col tile: [bcol-512, bcol+768)
#define BM    256
#define BN    256

typedef __bf16 bf16x8 __attribute__((ext_vector_type(8)));
typedef float  f32x4  __attribute__((ext_vector_type(4)));

__device__ __forceinline__ int band_start(int o) {
    if (o <= 512)  return o * 513 + ((o * (o - 1)) >> 1);
    if (o <= 3584) return 393472 + (o - 512) * 1025;
    const int d = o - 3584;
    return 3542272 + (((1024 + 4609 - o) * d) >> 1);
}

__device__ __forceinline__ uint16_t f32_to_bf16(float f) {
    uint32_t u = __builtin_bit_cast(uint32_t, f);
    u += 0x7FFFu + ((u >> 16) & 1u);   // RNE
    return (uint16_t)(u >> 16);
}

// ---- pass 1: x fp32 -> bf16 dense [M][4096]
__global__ __launch_bounds__(256) void cvt_x(const float* __restrict__ x,
                                             uint16_t* __restrict__ xb, int n4) {
    const int stride = gridDim.x * 256;
    for (int i = blockIdx.x * 256 + threadIdx.x; i < n4; i += stride) {
        const float4 v = reinterpret_cast<const float4*>(x)[i];
        const uint32_t lo = (uint32_t)f32_to_bf16(v.x) | ((uint32_t)f32_to_bf16(v.y) << 16);
        const uint32_t hi = (uint32_t)f32_to_bf16(v.z) | ((uint32_t)f32_to_bf16(v.w) << 16);
        reinterpret_cast<uint2*>(xb)[i] = make_uint2(lo, hi);
    }
}

// ---- pass 2: densify band -> wd[o][j], j indexes k = (o&~255)-512+j, zero outside band
__global__ __launch_bounds__(256) void cvt_w(const float* __restrict__ wv,
                                             uint16_t* __restrict__ wd) {
    const int o = blockIdx.y;
    const int j = blockIdx.x * 256 + threadIdx.x;     // 0..1279
    const int i = (o & ~(BM - 1)) - BW + j;
    uint16_t v = 0;
    if (i >= o - BW && i <= o + BW && i >= 0 && i < IN_F) {
        const int lo = (o > BW) ? (o - BW) : 0;
        v = f32_to_bf16(wv[band_start(o) + (i - lo)]);
    }
    wd[o * WB2 + j] = v;
}

// ---- pass 3: v9 ring-9 structure, NO setprio, persistent 2-row blocks (1/CU).
__global__ __launch_bounds__(512, 1) void band_gemm_v10(
    const uint16_t* __restrict__ xb,
    const uint16_t* __restrict__ wd,
    const float* __restrict__ bias,
    float* __restrict__ out)
{
    __shared__ __align__(128) uint8_t lds[9 * 16384];   // 144 KB, 9 unit slots

    // bx-grouped XCD mapping on 256 blocks: XCD x owns column panels {2x, 2x+1}
    const int id  = blockIdx.x;
    const int bx  = 2 * (id & 7) + ((id >> 3) & 1);
    const int byg = id >> 4;                 // 0..15 ; block does rows byg and byg+16
    const int bcol = bx * BN;
    const int brow0 = byg * BM;

    const int wlo    = bcol - BW;
    const int kstart = wlo > 0 ? wlo : 0;
    const int kend   = (bcol + BN + BW) < IN_F ? (bcol + BN + BW) : IN_F;
    const int nt     = (kend - kstart) >> 6;      // 12/16/20 K64 tiles
    const int j0     = kstart - wlo;

    const int tid  = threadIdx.x;
    const int w    = tid >> 6;
    const int lane = tid & 63;
    const int ln   = lane & 15;
    const int kc   = lane >> 4;
    const int wm   = w >> 2;            // 0..1  (M half, 128 rows)
    const int wn   = w & 3;             // 0..3  (N quarter, 64 cols)

    // staging: unit = 128 rows x 128 B (16 KB = 2 gloads of 64 rows each)
    // LDS(row,c) holds global chunk c ^ (row&7)  [chunk = 16 B] -> pre-swizzled src
    const int srow = tid >> 3;          // 0..63
    const int csrc = (tid & 7) ^ (srow & 7);
    const uint16_t* aSrc0 = xb + (size_t)(brow0 + srow) * IN_F + kstart + csrc * 8;
    const uint16_t* aSrc1 = aSrc0 + (size_t)16 * BM * IN_F;      // rows +4096
    const uint16_t* bSrc  = wd + (size_t)(bcol + srow) * WB2 + j0 + csrc * 8;

#define GLOAD(srcp, dst_off)                                                             \
    __builtin_amdgcn_global_load_lds(                                                    \
        (const __attribute__((address_space(1))) uint32_t*)(srcp),                       \
        (__attribute__((address_space(3))) uint32_t*)(lds + (dst_off) + (w << 10)),      \
        16, 0, 0)

    // unit j of tile w_: j=0 A rows 0-127, j=1 B rows 0-127, j=2 A rows 128-255, j=3 B rows 128-255
#define STG_UNIT(AS, w_, j_, slot_) {                                                    \
        if (((j_) & 1) == 0) {                                                           \
            const uint16_t* p_ = (AS) + (size_t)(((j_) >> 1) * 128) * IN_F + (w_) * 64;  \
            GLOAD(p_, (slot_) << 14);                                                    \
            GLOAD(p_ + (size_t)64 * IN_F, ((slot_) << 14) + 8192);                       \
        } else {                                                                         \
            const uint16_t* p_ = bSrc + (size_t)(((j_) >> 1) * 128) * WB2 + (w_) * 64;   \
            GLOAD(p_, (slot_) << 14);                                                    \
            GLOAD(p_ + (size_t)64 * WB2, ((slot_) << 14) + 8192);                        \
        } }

    // fragment addressing within a 16 KB unit (proven zero-conflict); k-step1 = ^64
    const int cswz = (kc ^ (ln & 7)) << 4;

#define LD_A(BASE, MQ) {                                                                 \
    _Pragma("unroll")                                                                    \
    for (int s_ = 0; s_ < 4; ++s_) {                                                     \
        const int off_ = (BASE) + (((MQ) * 64 + s_ * 16 + ln) << 7) + cswz;              \
        am[s_][0] = *(const bf16x8*)(lds + off_);                                        \
        am[s_][1] = *(const bf16x8*)(lds + (off_ ^ 64));                                 \
    } }
#define LD_B(DST, BASE, NQ) {                                                            \
    _Pragma("unroll")                                                                    \
    for (int s_ = 0; s_ < 2; ++s_) {                                                     \
        const int off_ = (BASE) + (((wn & 1) * 64 + (NQ) * 32 + s_ * 16 + ln) << 7) + cswz; \
        DST[s_][0] = *(const bf16x8*)(lds + off_);                                       \
        DST[s_][1] = *(const bf16x8*)(lds + (off_ ^ 64));                                \
    } }
#define MFMAPH(MROW, NCOL, BB) {                                                         \
    _Pragma("unroll")                                                                    \
    for (int a_ = 0; a_ < 4; ++a_) {                                                     \
        _Pragma("unroll")                                                                \
        for (int n_ = 0; n_ < 2; ++n_) {                                                 \
            acc[(MROW) + a_][(NCOL) + n_] = __builtin_amdgcn_mfma_f32_16x16x32_bf16(     \
                am[a_][0], BB[n_][0], acc[(MROW) + a_][(NCOL) + n_], 0, 0, 0);           \
            acc[(MROW) + a_][(NCOL) + n_] = __builtin_amdgcn_mfma_f32_16x16x32_bf16(     \
                am[a_][1], BB[n_][1], acc[(MROW) + a_][(NCOL) + n_], 0, 0, 0);           \
        } } }

#define PRO(AS) {                                                                        \
    STG_UNIT(AS, 0, 0, 0); STG_UNIT(AS, 0, 1, 1); STG_UNIT(AS, 0, 2, 2);                 \
    STG_UNIT(AS, 0, 3, 3); STG_UNIT(AS, 1, 0, 4); }

#define KLOOP(AS) {                                                                      \
    int s4v = 0;                                                                         \
    for (int v = 0; v < nt; ++v) {                                                       \
        int sA = s4v + (wm << 1);            if (sA >= 9) sA -= 9;                       \
        int sB = s4v + 1 + ((wn >> 1) << 1); if (sB >= 9) sB -= 9;                       \
        const int aBase = sA << 14, bBase = sB << 14;                                    \
        int st0 = s4v + 5; if (st0 >= 9) st0 -= 9;                                       \
        int st1 = st0 + 1; if (st1 >= 9) st1 -= 9;                                       \
        int st2 = st1 + 1; if (st2 >= 9) st2 -= 9;                                       \
        int st3 = st2 + 1; if (st3 >= 9) st3 -= 9;                                       \
        const bool stg_q012 = (v + 1 < nt);                                              \
        const bool stg_q3   = (v + 2 < nt);                                              \
        LD_A(aBase, 0);                                                                  \
        LD_B(bn0, bBase, 0);                                                             \
        if (stg_q012) STG_UNIT(AS, v + 1, 1, st0);                                       \
        MFMAPH(0, 0, bn0);                                                               \
        LD_B(bn1, bBase, 1);                                                             \
        if (stg_q012) STG_UNIT(AS, v + 1, 2, st1);                                       \
        MFMAPH(0, 2, bn1);                                                               \
        LD_A(aBase, 1);                                                                  \
        if (stg_q012) STG_UNIT(AS, v + 1, 3, st2);                                       \
        MFMAPH(4, 2, bn1);                                                               \
        if (stg_q3) STG_UNIT(AS, v + 2, 0, st3);                                         \
        MFMAPH(4, 0, bn0);                                                               \
        if (v + 1 < nt) {                                                                \
            if (v + 2 < nt) { asm volatile("s_waitcnt vmcnt(2)" ::: "memory"); }         \
            else            { asm volatile("s_waitcnt vmcnt(0)" ::: "memory"); }         \
            __builtin_amdgcn_s_barrier();                                                \
        }                                                                                \
        s4v += 4; if (s4v >= 9) s4v -= 9;                                                \
    } }

    // epilogue: C/D map col = lane&15, row = (lane>>4)*4 + q  (verified R2-R9)
#define EPI(BROWX) {                                                                     \
    _Pragma("unroll")                                                                    \
    for (int a_ = 0; a_ < 8; ++a_) {                                                     \
        _Pragma("unroll")                                                                \
        for (int q_ = 0; q_ < 4; ++q_) {                                                 \
            const int row_ = (BROWX) + wm * 128 + a_ * 16 + (kc << 2) + q_;              \
            float* po_ = out + (size_t)row_ * OUT_F + ocol;                              \
            _Pragma("unroll")                                                            \
            for (int n_ = 0; n_ < 4; ++n_)                                               \
                po_[n_ * 16] = acc[a_][n_][q_] + bsv[n_];                                 \
        } } }

    const int ocol = bcol + wn * 64 + ln;
    float bsv[4];
    #pragma unroll
    for (int n = 0; n < 4; ++n) bsv[n] = bias[ocol + n * 16];

    f32x4 acc[8][4] = {};
    bf16x8 am[4][2], bn0[2][2], bn1[2][2];

    // ---- row-tile g=0
    PRO(aSrc0);
    asm volatile("s_waitcnt vmcnt(2)" ::: "memory");
    __builtin_amdgcn_s_barrier();
    KLOOP(aSrc0);
    __builtin_amdgcn_s_barrier();            // slot safety: all g0 reads complete

    // ---- g=1 prologue; epilogue-0 stores drain under g1 compute
    PRO(aSrc1);
    asm volatile("s_waitcnt vmcnt(2)" ::: "memory");
    __builtin_amdgcn_s_barrier();
    EPI(brow0);
    #pragma unroll
    for (int a = 0; a < 8; ++a)
        #pragma unroll
        for (int n = 0; n < 4; ++n) acc[a][n] = (f32x4){0.f, 0.f, 0.f, 0.f};
    KLOOP(aSrc1);
    EPI(brow0 + 16 * BM);

#undef STG_UNIT
#undef GLOAD
#undef PRO
#undef KLOOP
#undef EPI
}

// ---- fallback (ws too small / odd M): fp32 tiled kernel, known correct
__global__ __launch_bounds__(256) void band_gemm_f32(
    const float* __restrict__ x, const float* __restrict__ wv,
    const float* __restrict__ bias, float* __restrict__ out, int M)
{
    __shared__ float Xs[128][33];
    __shared__ float Ws[32][130];
    const int tid = threadIdx.x;
    const int tx = tid & 15, ty = tid >> 4;
    const int bcol = blockIdx.x * 128, brow = blockIdx.y * 128;
    const int klo = (bcol >= BW) ? (bcol - BW) : 0;
    const int khi = min(IN_F, bcol + 128 + BW);
    float acc[8][8];
    #pragma unroll
    for (int a = 0; a < 8; ++a)
        #pragma unroll
        for (int b = 0; b < 8; ++b) acc[a][b] = 0.f;
    const int xc4 = (tid & 7) * 4, xr0 = tid >> 3;
    const int wc = tid & 31, wr0 = tid >> 5;
    for (int k0 = klo; k0 < khi; k0 += 32) {
        #pragma unroll
        for (int p = 0; p < 4; ++p) {
            const int rr = xr0 + 32 * p;
            const float4 v = *reinterpret_cast<const float4*>(&x[(size_t)(brow + rr) * IN_F + (k0 + xc4)]);
            Xs[rr][xc4 + 0] = v.x; Xs[rr][xc4 + 1] = v.y; Xs[rr][xc4 + 2] = v.z; Xs[rr][xc4 + 3] = v.w;
        }
        const int i = k0 + wc;
        #pragma unroll
        for (int p = 0; p < 16; ++p) {
            const int rr = wr0 + 8 * p;
            const int o = bcol + rr;
            const int lo = (o >= BW) ? (o - BW) : 0;
            float v = 0.f;
            if (i >= o - BW && i <= o + BW) v = wv[band_start(o) + (i - lo)];
            Ws[wc][rr] = v;
        }
        __syncthreads();
        #pragma unroll
        for (int k = 0; k < 32; ++k) {
            float amv[8];
            #pragma unroll
            for (int a = 0; a < 8; ++a) amv[a] = Xs[ty * 8 + a][k];
            float bo[8];
            #pragma unroll
            for (int b = 0; b < 4; ++b) { bo[b] = Ws[k][tx * 4 + b]; bo[4 + b] = Ws[k][tx * 4 + 64 + b]; }
            #pragma unroll
            for (int a = 0; a < 8; ++a)
                #pragma unroll
                for (int b = 0; b < 8; ++b) acc[a][b] = fmaf(amv[a], bo[b], acc[a][b]);
        }
        __syncthreads();
    }
    #pragma unroll
    for (int a = 0; a < 8; ++a) {
        const size_t row = (size_t)(brow + ty * 8 + a);
        #pragma unroll
        for (int b = 0; b < 4; ++b) {
            out[row * OUT_F + bcol + tx * 4 + b]      = acc[a][b]     + bias[bcol + tx * 4 + b];
            out[row * OUT_F + bcol + tx * 4 + 64 + b] = acc[a][4 + b] + bias[bcol + tx * 4 + 64 + b];
        }
    }
}

extern "C" void kernel_launch(void* const* d_in, const int* in_sizes, int n_in,
                              void* d_out, int out_size, void* d_ws, size_t ws_size,
                              hipStream_t stream) {
    const float* x    = (const float*)d_in[0];
    const float* wv   = (const float*)d_in[1];
    const float* bias = (const float*)d_in[2];
    float* out        = (float*)d_out;

    const int M = in_sizes[0] / IN_F;                         // 8192
    const size_t xb_bytes = (size_t)M * IN_F * 2;             // 64 MB
    const size_t wd_bytes = (size_t)OUT_F * WB2 * 2;          // 10.5 MB

    if (ws_size >= xb_bytes + wd_bytes && M == 8192) {
        uint16_t* xb  = (uint16_t*)d_ws;
        uint16_t* wdp = (uint16_t*)((uint8_t*)d_ws + xb_bytes);
        cvt_x<<<2048, 256, 0, stream>>>(x, xb, M * IN_F / 4);
        cvt_w<<<dim3(WB2 / 256, OUT_F), 256, 0, stream>>>(wv, wdp);
        band_gemm_v10<<<256, 512, 0, stream>>>(xb, wdp, bias, out);
    } else {
        dim3 grid(OUT_F / 128, M / 128);
        band_gemm_f32<<<grid, 256, 0, stream>>>(x, wv, bias, out, M);
    }
}